// Round 1
// baseline (79.886 us; speedup 1.0000x reference)
//
#include <hip/hip_runtime.h>
#include <math.h>

#define OUT_H 7
#define OUT_W 7
#define N_C 256
#define FH 38
#define FW 38
#define NUM_ROIS 256
#define SPATIAL_SCALE 0.0625f

// One thread per output element (roi, c, i, j). Output layout matches the
// reference: [roi][c][i][j], j fastest -> out[t] with t = global thread id
// gives fully coalesced stores. Each block (256 threads) covers ~5.2 channels
// of a single roi (49 blocks per roi exactly), so the 5 roi floats broadcast
// from L1 and the feature reads have strong spatial locality.
__global__ __launch_bounds__(256) void roi_pool_kernel(
    const float* __restrict__ feat,
    const float* __restrict__ rois,
    float* __restrict__ out)
{
    int t = blockIdx.x * blockDim.x + threadIdx.x;

    int j = t % OUT_W;
    int i = (t / OUT_W) % OUT_H;
    int c = (t / (OUT_W * OUT_H)) % N_C;
    int r = t / (OUT_W * OUT_H * N_C);

    const float* roi = rois + r * 5;
    int b  = (int)roi[0];
    int x1 = (int)(roi[1] * SPATIAL_SCALE);  // floor, values >= 0
    int y1 = (int)(roi[2] * SPATIAL_SCALE);
    int x2 = (int)(roi[3] * SPATIAL_SCALE);
    int y2 = (int)(roi[4] * SPATIAL_SCALE);
    int rh = y2 - y1 + 1;
    int rw = x2 - x1 + 1;

    // Python floor-div on non-negative ints == C int div
    int hstart = y1 + (i * rh) / OUT_H;
    int hend   = y1 + ((i + 1) * rh + OUT_H - 1) / OUT_H;
    int wstart = x1 + (j * rw) / OUT_W;
    int wend   = x1 + ((j + 1) * rw + OUT_W - 1) / OUT_W;

    const float* fp = feat + ((size_t)b * N_C + c) * (FH * FW);
    float m = -INFINITY;
    for (int h = hstart; h < hend; ++h) {
        const float* row = fp + h * FW;
        for (int w = wstart; w < wend; ++w) {
            m = fmaxf(m, row[w]);
        }
    }
    out[t] = m;
}

extern "C" void kernel_launch(void* const* d_in, const int* in_sizes, int n_in,
                              void* d_out, int out_size, void* d_ws, size_t ws_size,
                              hipStream_t stream) {
    const float* feat = (const float*)d_in[0];
    const float* rois = (const float*)d_in[1];
    float* out = (float*)d_out;

    int total = NUM_ROIS * N_C * OUT_H * OUT_W;  // 3,211,264
    int block = 256;
    int grid = (total + block - 1) / block;       // 12544
    roi_pool_kernel<<<grid, block, 0, stream>>>(feat, rois, out);
}